// Round 6
// baseline (97.260 us; speedup 1.0000x reference)
//
#include <hip/hip_runtime.h>

#define NB    64
#define IN    512
#define OUT   512
#define NTOK  512       // B*T
#define NSEL  1024      // NTOK*K
#define NQ    4         // row quarters
#define RQ    128       // rows per quarter
#define TCAP  16        // token slots per pass
#define ELMAX 256       // per-bank selection-list capacity (mean n=16, huge margin)
#define XSTR  132       // xs float stride per slot (128 + 4 pad)

// Block = (bank, 64-col tile, 128-row quarter). 256 threads, 4 waves:
//   wave w = 32-row slice; lane: ct = l&15 (float4 col), g = l>>4 (token
//   subgroup -> W addr independent of g: 4-way in-wave dup, dedup'd/broadcast).
// Thread: acc over 4 token slots (4j+g) x 4 cols; W fragment read once.
// Cross-wave reduce: ds_add_f32 into red (aliases xs). Per-selection stores.
__global__ __launch_bounds__(256) void banked_gemv(
    const float* __restrict__ x,      // [NTOK][IN]
    const int*   __restrict__ sel,    // [NSEL]
    const float* __restrict__ probs,  // [NSEL]
    const float* __restrict__ W,      // [NB][IN][OUT]
    const float* __restrict__ bias,   // [NB][OUT]
    float* __restrict__ ysel)         // [NSEL][NQ][OUT]
{
    __shared__ __align__(16) float xs[TCAP * XSTR];   // 8448 B; red aliases 4 KB
    __shared__ int   elist[ELMAX];
    __shared__ int   lcnt;
    __shared__ int   tok_s[TCAP];
    __shared__ float prob_s[TCAP];

    const int bank = blockIdx.x >> 5;         // 64
    const int tile = (blockIdx.x >> 2) & 7;   // 8
    const int q    = blockIdx.x & 3;          // 4
    const int t    = threadIdx.x;

    // build this bank's selection list (slot order is free; per-selection
    // math is slot-invariant)
    if (t == 0) lcnt = 0;
    __syncthreads();
    {
        const int4 s4 = reinterpret_cast<const int4*>(sel)[t];
        if (s4.x == bank) elist[atomicAdd(&lcnt, 1)] = 4 * t;
        if (s4.y == bank) elist[atomicAdd(&lcnt, 1)] = 4 * t + 1;
        if (s4.z == bank) elist[atomicAdd(&lcnt, 1)] = 4 * t + 2;
        if (s4.w == bank) elist[atomicAdd(&lcnt, 1)] = 4 * t + 3;
    }
    __syncthreads();
    const int n = lcnt;
    if (n == 0) return;

    const int l  = t & 63;
    const int w  = t >> 6;      // wave = 32-row slice
    const int ct = l & 15;      // float4 col within 64-col tile
    const int g  = l >> 4;      // token subgroup 0..3
    const int col0 = tile * 64;
    const int row0 = q * RQ + w * 32;
    const float* wbase = W + (size_t)bank * (IN * OUT) + (size_t)row0 * OUT + col0 + ct * 4;
    float4* red = reinterpret_cast<float4*>(xs);   // [TCAP][16] float4 = 4 KB

    for (int c0 = 0; c0 < n; c0 += TCAP) {
        if (t < TCAP) {
            const int idx = c0 + t;
            const int e = (idx < n) ? elist[idx] : -1;
            tok_s[t]  = (e >= 0) ? (e >> 1) : 0;
            prob_s[t] = (e >= 0) ? probs[e] : 0.0f;
        }
        __syncthreads();

        // stage xs pre-scaled: 16 slots x 32 float4 (this quarter's rows); 2/thread
        #pragma unroll
        for (int k2 = 0; k2 < 2; ++k2) {
            const int oid  = t + k2 * 256;
            const int slot = oid >> 5;
            const int c4   = oid & 31;
            float4 v = *reinterpret_cast<const float4*>(
                x + (size_t)tok_s[slot] * IN + q * RQ + c4 * 4);
            const float p = prob_s[slot];
            v.x *= p; v.y *= p; v.z *= p; v.w *= p;
            *reinterpret_cast<float4*>(xs + slot * XSTR + c4 * 4) = v;
        }
        __syncthreads();

        float4 acc[4];
        #pragma unroll
        for (int j = 0; j < 4; ++j) acc[j] = make_float4(0.f, 0.f, 0.f, 0.f);

        #pragma unroll 2
        for (int chunk = 0; chunk < 8; ++chunk) {
            const float* wr = wbase + (size_t)(chunk * 4) * OUT;
            const float4 w0 = *reinterpret_cast<const float4*>(wr);
            const float4 w1 = *reinterpret_cast<const float4*>(wr + OUT);
            const float4 w2 = *reinterpret_cast<const float4*>(wr + 2 * OUT);
            const float4 w3 = *reinterpret_cast<const float4*>(wr + 3 * OUT);
            #pragma unroll
            for (int j = 0; j < 4; ++j) {
                const float4 xv = *reinterpret_cast<const float4*>(
                    xs + (4 * j + g) * XSTR + (w * 32 + chunk * 4));
                acc[j].x += xv.x * w0.x + xv.y * w1.x + xv.z * w2.x + xv.w * w3.x;
                acc[j].y += xv.x * w0.y + xv.y * w1.y + xv.z * w2.y + xv.w * w3.y;
                acc[j].z += xv.x * w0.z + xv.y * w1.z + xv.z * w2.z + xv.w * w3.z;
                acc[j].w += xv.x * w0.w + xv.y * w1.w + xv.z * w2.w + xv.w * w3.w;
            }
        }
        __syncthreads();   // xs consumed; reuse as red

        red[t] = make_float4(0.f, 0.f, 0.f, 0.f);   // 256 f4 = whole red
        __syncthreads();

        #pragma unroll
        for (int j = 0; j < 4; ++j) {
            float* rp = reinterpret_cast<float*>(&red[(4 * j + g) * 16 + ct]);
            atomicAdd(rp + 0, acc[j].x);
            atomicAdd(rp + 1, acc[j].y);
            atomicAdd(rp + 2, acc[j].z);
            atomicAdd(rp + 3, acc[j].w);
        }
        __syncthreads();

        // store: 16 slots x 16 float4-cols = 256 outputs, 1/thread
        {
            const int slot = t >> 4;
            const int c    = t & 15;
            if (c0 + slot < n) {
                float4 sum = red[slot * 16 + c];
                if (q == 0) {
                    const float p = prob_s[slot];
                    const float4 bv = *reinterpret_cast<const float4*>(
                        bias + bank * OUT + col0 + c * 4);
                    sum.x += p * bv.x; sum.y += p * bv.y;
                    sum.z += p * bv.z; sum.w += p * bv.w;
                }
                const int e = elist[c0 + slot];
                *reinterpret_cast<float4*>(
                    ysel + ((size_t)e * NQ + q) * OUT + col0 + c * 4) = sum;
            }
        }
        __syncthreads();   // before restaging xs / refilling tok_s
    }
}

// out[t] = sum over (k=2 selections) x (4 quarters)
__global__ __launch_bounds__(256) void combine(const float* __restrict__ ysel,
                                               float* __restrict__ out) {
    const int i  = blockIdx.x * 256 + threadIdx.x;   // float4 index, 65536
    const int tk = i >> 7;
    const int c  = i & 127;
    const float4* y4 = reinterpret_cast<const float4*>(ysel);
    const size_t b0 = (size_t)(2 * tk) * NQ * 128;   // e=2tk block, f4 units
    float4 r = make_float4(0.f, 0.f, 0.f, 0.f);
    #pragma unroll
    for (int e2 = 0; e2 < 2; ++e2) {
        #pragma unroll
        for (int qq = 0; qq < NQ; ++qq) {
            const float4 v = y4[b0 + (size_t)e2 * NQ * 128 + qq * 128 + c];
            r.x += v.x; r.y += v.y; r.z += v.z; r.w += v.w;
        }
    }
    reinterpret_cast<float4*>(out)[i] = r;
}

extern "C" void kernel_launch(void* const* d_in, const int* in_sizes, int n_in,
                              void* d_out, int out_size, void* d_ws, size_t ws_size,
                              hipStream_t stream) {
    const float* x     = (const float*)d_in[0];
    const int*   sel   = (const int*)d_in[1];
    const float* probs = (const float*)d_in[2];
    const float* W     = (const float*)d_in[3];
    const float* bias  = (const float*)d_in[4];
    float* out  = (float*)d_out;
    float* ysel = (float*)d_ws;     // [NSEL][NQ][OUT] = 8 MB

    banked_gemv<<<NB * 8 * NQ, 256, 0, stream>>>(x, sel, probs, W, bias, ysel);
    combine<<<(NTOK * OUT / 4) / 256, 256, 0, stream>>>(ysel, out);
}